// Round 8
// baseline (405.027 us; speedup 1.0000x reference)
//
#include <hip/hip_runtime.h>
#include <hip/hip_bf16.h>

#define NBATCH 4
#define SEQ    2048
#define EMBED  1024
#define HEADS  16
#define HD     64

typedef __attribute__((ext_vector_type(8))) short bf16x8;
typedef __attribute__((ext_vector_type(4))) float f32x4;
typedef __attribute__((ext_vector_type(16))) float f32x16;

__device__ __forceinline__ short f2bf(float f) {
  union { float f; unsigned u; } v; v.f = f;
  unsigned r = v.u + 0x7fffu + ((v.u >> 16) & 1u);
  return (short)(r >> 16);
}

__device__ __forceinline__ unsigned pkbf(float a, float b) {
#if __has_builtin(__builtin_amdgcn_cvt_pk_bf16_f32)
  typedef __attribute__((ext_vector_type(2))) __bf16 bf16x2_t;
  bf16x2_t r = __builtin_amdgcn_cvt_pk_bf16_f32(a, b);
  union { bf16x2_t v; unsigned u; } cv; cv.v = r; return cv.u;
#else
  return (unsigned)(unsigned short)f2bf(a) | ((unsigned)(unsigned short)f2bf(b) << 16);
#endif
}

typedef __attribute__((address_space(1))) const void gas_void;
typedef __attribute__((address_space(3))) void las_void;
__device__ __forceinline__ void glds16(const void* g, void* l) {
  __builtin_amdgcn_global_load_lds((gas_void*)g, (las_void*)l, 16, 0, 0);
}

__device__ __forceinline__ bf16x8 mk8(unsigned a, unsigned b, unsigned c, unsigned d) {
  union { unsigned u[4]; bf16x8 v; } t;
  t.u[0] = a; t.u[1] = b; t.u[2] = c; t.u[3] = d; return t.v;
}

__device__ __forceinline__ void pl32swap(unsigned &a, unsigned &b) {
  asm volatile("v_permlane32_swap_b32 %0, %1" : "+v"(a), "+v"(b));
}

#define MFMA32(A, B, C) __builtin_amdgcn_mfma_f32_32x32x16_bf16((A), (B), (C), 0, 0, 0)

#define C2 0.04508422f  // log2(e) / sqrt(1024), folded into Wq at conversion

// ---------------- fused weight conversion (Wo + Wq*C2 + Wk + Wv) ----------------
__global__ __launch_bounds__(256) void cvt_all(
    const float* __restrict__ Wo, const float* __restrict__ Wq,
    const float* __restrict__ Wk, const float* __restrict__ Wv,
    short* __restrict__ dWo, short* __restrict__ dWq,
    short* __restrict__ dWk, short* __restrict__ dWv)
{
  int e = (blockIdx.x * 256 + threadIdx.x) * 4;
  const float* src; short* dst; int off; float sc = 1.0f;
  if (e < EMBED * EMBED) { src = Wo; dst = dWo; off = e; }
  else {
    int j = e - EMBED * EMBED;
    if      (j < 4096)  { src = Wq; dst = dWq; off = j; sc = C2; }
    else if (j < 8192)  { src = Wk; dst = dWk; off = j - 4096; }
    else if (j < 12288) { src = Wv; dst = dWv; off = j - 8192; }
    else return;
  }
  float4 v = *(const float4*)(src + off);
  ushort4 p;
  p.x = (unsigned short)f2bf(v.x * sc);
  p.y = (unsigned short)f2bf(v.y * sc);
  p.z = (unsigned short)f2bf(v.z * sc);
  p.w = (unsigned short)f2bf(v.w * sc);
  *(ushort4*)(dst + off) = p;
}

// ---------------- mask (int32 0/1) -> bitmask, 4 elems/thread (R6, kept) ----------------
__global__ __launch_bounds__(256) void mask_pack(const int* __restrict__ mask,
                                                 unsigned long long* __restrict__ bits) {
  long long base = (long long)blockIdx.x * 1024;
  int tid = threadIdx.x, lane = tid & 63, wv = tid >> 6;
  const int* p = mask + base + wv * 256 + lane;
  int m0 = p[0], m1 = p[64], m2 = p[128], m3 = p[192];
  unsigned long long b0 = __ballot(m0 != 0);
  unsigned long long b1 = __ballot(m1 != 0);
  unsigned long long b2 = __ballot(m2 != 0);
  unsigned long long b3 = __ballot(m3 != 0);
  if (lane == 0) {
    unsigned long long* d = bits + (base >> 6) + wv * 4;
    ulonglong2 w0; w0.x = b0; w0.y = b1;
    ulonglong2 w1; w1.x = b2; w1.y = b3;
    *(ulonglong2*)(d)     = w0;
    *(ulonglong2*)(d + 2) = w1;
  }
}

// ---------------- QKV projection (R4, passed) ----------------
__global__ __launch_bounds__(256) void proj_kernel(
    const float* __restrict__ srcQ, const float* __restrict__ srcK, const float* __restrict__ srcV,
    const short* __restrict__ WbQ, const short* __restrict__ WbK, const short* __restrict__ WbV,
    short* __restrict__ Qp, short* __restrict__ Kp, short* __restrict__ Vt)
{
  int rt = blockIdx.x;
  int h  = blockIdx.y;
  int mz = blockIdx.z;
  const float* src = (mz == 0) ? srcQ : ((mz == 1) ? srcK : srcV);
  const short* Wb  = (mz == 0) ? WbQ : ((mz == 1) ? WbK : WbV);

  __shared__ __align__(16) short At[64][72];

  int tid = threadIdx.x;
  int r0 = rt * 64;
  for (int idx = tid; idx < 64 * 16; idx += 256) {
    int row = idx >> 4;
    int c4  = idx & 15;
    float4 v = *(const float4*)(src + (long long)(r0 + row) * EMBED + h * HD + c4 * 4);
    uint2 pk2;
    pk2.x = pkbf(v.x, v.y);
    pk2.y = pkbf(v.z, v.w);
    *(uint2*)&At[row][c4 * 4] = pk2;
  }
  __syncthreads();

  int lane = tid & 63, w = tid >> 6, quad = lane >> 4, l15 = lane & 15;

  bf16x8 af0 = *(const bf16x8*)&At[w * 16 + l15][quad * 8];
  bf16x8 af1 = *(const bf16x8*)&At[w * 16 + l15][32 + quad * 8];

  f32x4 acc[4];
  for (int cg = 0; cg < 4; cg++) {
    acc[cg] = (f32x4){0.f, 0.f, 0.f, 0.f};
    bf16x8 b0 = *(const bf16x8*)(Wb + (cg * 16 + l15) * 64 + quad * 8);
    bf16x8 b1 = *(const bf16x8*)(Wb + (cg * 16 + l15) * 64 + 32 + quad * 8);
    acc[cg] = __builtin_amdgcn_mfma_f32_16x16x32_bf16(af0, b0, acc[cg], 0, 0, 0);
    acc[cg] = __builtin_amdgcn_mfma_f32_16x16x32_bf16(af1, b1, acc[cg], 0, 0, 0);
  }

  int rloc = w * 16 + quad * 4;
  __syncthreads();
  if (mz < 2) {
#pragma unroll
    for (int cg = 0; cg < 4; cg++)
#pragma unroll
      for (int reg = 0; reg < 4; reg++)
        At[rloc + reg][cg * 16 + l15] = f2bf(acc[cg][reg]);
  } else {
#pragma unroll
    for (int cg = 0; cg < 4; cg++)
#pragma unroll
      for (int reg = 0; reg < 4; reg++)
        At[cg * 16 + l15][rloc + reg] = f2bf(acc[cg][reg]);
  }
  __syncthreads();

  short* dst = (mz == 0) ? Qp : ((mz == 1) ? Kp : Vt);
  int row2 = tid >> 2, ch = tid & 3;
  const uint4* lp = (const uint4*)&At[row2][ch * 16];
  uint4 v0 = lp[0], v1 = lp[1];
  char* g;
  if (mz < 2) {
    int r = r0 + row2; int n = r >> 11, s = r & 2047;
    g = (char*)(dst + ((long long)(n * HEADS + h) * SEQ + s) * HD) + ch * 32;
  } else {
    int n = r0 >> 11, s0 = r0 & 2047;
    g = (char*)(dst + ((long long)(n * HEADS + h) * HD + row2) * SEQ + s0) + ch * 32;
  }
  *(uint4*)g = v0;
  *(uint4*)(g + 16) = v1;
}

// ---------------- flash attention: R7 body + additive LUT masking ----------------
// R8: VALUBusy 64% x 122us = ~78us of VALU issue; the largest removable block is
// per-element predicated masking (v_and+v_cmp+v_cndmask x32/iter ~= 190cy/iter/wave).
// Replace with additive masking: p = exp2(s + m), m in {0, -16384} from a 16-entry
// LDS LUT keyed by mask nibble (exp2(s-16384) == +0.0f exactly -> P and lsum
// contributions identical to the cndmask path). LUT reads issued before each MFMA
// cluster so ds_read latency hides under MFMA; <=16 extra VGPRs live at a time.
#define SOFTMAX_KK(SV, M0, M1, M2, M3, PAV0, PAV1) do {                           \
    float p0  = __builtin_amdgcn_exp2f(SV[0]  + M0[0]);                           \
    float p1  = __builtin_amdgcn_exp2f(SV[1]  + M0[1]);                           \
    float p2  = __builtin_amdgcn_exp2f(SV[2]  + M0[2]);                           \
    float p3  = __builtin_amdgcn_exp2f(SV[3]  + M0[3]);                           \
    float p4  = __builtin_amdgcn_exp2f(SV[4]  + M1[0]);                           \
    float p5  = __builtin_amdgcn_exp2f(SV[5]  + M1[1]);                           \
    float p6  = __builtin_amdgcn_exp2f(SV[6]  + M1[2]);                           \
    float p7  = __builtin_amdgcn_exp2f(SV[7]  + M1[3]);                           \
    float p8  = __builtin_amdgcn_exp2f(SV[8]  + M2[0]);                           \
    float p9  = __builtin_amdgcn_exp2f(SV[9]  + M2[1]);                           \
    float p10 = __builtin_amdgcn_exp2f(SV[10] + M2[2]);                           \
    float p11 = __builtin_amdgcn_exp2f(SV[11] + M2[3]);                           \
    float p12 = __builtin_amdgcn_exp2f(SV[12] + M3[0]);                           \
    float p13 = __builtin_amdgcn_exp2f(SV[13] + M3[1]);                           \
    float p14 = __builtin_amdgcn_exp2f(SV[14] + M3[2]);                           \
    float p15 = __builtin_amdgcn_exp2f(SV[15] + M3[3]);                           \
    lsum += (((p0 + p1) + (p2 + p3)) + ((p4 + p5) + (p6 + p7)))                   \
          + (((p8 + p9) + (p10 + p11)) + ((p12 + p13) + (p14 + p15)));            \
    unsigned u0 = pkbf(p0, p1),   u1 = pkbf(p2, p3);                              \
    unsigned u2 = pkbf(p4, p5),   u3 = pkbf(p6, p7);                              \
    unsigned u4 = pkbf(p8, p9),   u5 = pkbf(p10, p11);                            \
    unsigned u6 = pkbf(p12, p13), u7 = pkbf(p14, p15);                            \
    pl32swap(u0, u2); pl32swap(u1, u3);                                           \
    pl32swap(u4, u6); pl32swap(u5, u7);                                           \
    PAV0 = mk8(u0, u1, u2, u3);                                                   \
    PAV1 = mk8(u4, u5, u6, u7);                                                   \
  } while (0)

#define LUTLD(MW, SH) (*(const f32x4*)lutm[((MW) >> (SH)) & 0xFu])

#define ATTN_ITER(BUF, KT) do {                                                   \
    __syncthreads();                                                              \
    unsigned mlo = (unsigned)mcur, mhiw = (unsigned)(mcur >> 32);                 \
    f32x4 M0 = LUTLD(mlo, sh4);                                                   \
    f32x4 M1 = LUTLD(mlo, sh4 + 8);                                               \
    f32x4 M2 = LUTLD(mlo, sh4 + 16);                                              \
    f32x4 M3 = LUTLD(mlo, sh4 + 24);                                              \
    if ((KT) < 31) {                                                              \
      const char* ks_ = Kb + ((KT) + 1) * 8192 + kgo;                             \
      const char* vs_ = Vb + ((KT) + 1) * 128 + vgo;                              \
      char* kd_ = ldsK + (((BUF) ^ 1) * 8192) + klo;                              \
      char* vd_ = ldsV + (((BUF) ^ 1) * 8192) + klo;                              \
      glds16(ks_,          kd_);                                                  \
      glds16(ks_ + 4096,   kd_ + 4096);                                           \
      glds16(vs_,          vd_);                                                  \
      glds16(vs_ + 131072, vd_ + 4096);                                           \
      mnxt = mptr[(KT) + 1];                                                      \
    }                                                                             \
    const char* KB_ = ldsK + (BUF) * 8192;                                        \
    const char* VB_ = ldsV + (BUF) * 8192;                                        \
    bf16x8 pa0, pa1, pa2, pa3;                                                    \
    {                                                                             \
      f32x16 s = {};                                                              \
      __builtin_amdgcn_s_setprio(1);                                              \
      s = MFMA32(*(const bf16x8*)(KB_ + a4_0), qf0, s);                           \
      s = MFMA32(*(const bf16x8*)(KB_ + a4_1), qf1, s);                           \
      s = MFMA32(*(const bf16x8*)(KB_ + a4_2), qf2, s);                           \
      s = MFMA32(*(const bf16x8*)(KB_ + a4_3), qf3, s);                           \
      __builtin_amdgcn_s_setprio(0);                                              \
      SOFTMAX_KK(s, M0, M1, M2, M3, pa0, pa1);                                    \
    }                                                                             \
    {                                                                             \
      f32x4 M4 = LUTLD(mhiw, sh4);                                                \
      f32x4 M5 = LUTLD(mhiw, sh4 + 8);                                            \
      f32x4 M6 = LUTLD(mhiw, sh4 + 16);                                           \
      f32x4 M7 = LUTLD(mhiw, sh4 + 24);                                           \
      f32x16 s = {};                                                              \
      __builtin_amdgcn_s_setprio(1);                                              \
      s = MFMA32(*(const bf16x8*)(KB_ + 4096 + a4_0), qf0, s);                    \
      s = MFMA32(*(const bf16x8*)(KB_ + 4096 + a4_1), qf1, s);                    \
      s = MFMA32(*(const bf16x8*)(KB_ + 4096 + a4_2), qf2, s);                    \
      s = MFMA32(*(const bf16x8*)(KB_ + 4096 + a4_3), qf3, s);                    \
      __builtin_amdgcn_s_setprio(0);                                              \
      SOFTMAX_KK(s, M4, M5, M6, M7, pa2, pa3);                                    \
    }                                                                             \
    __builtin_amdgcn_s_setprio(1);                                                \
    O0 = MFMA32(*(const bf16x8*)(VB_ + a4_0),        pa0, O0);                    \
    O1 = MFMA32(*(const bf16x8*)(VB_ + 4096 + a4_0), pa0, O1);                    \
    O0 = MFMA32(*(const bf16x8*)(VB_ + a4_1),        pa1, O0);                    \
    O1 = MFMA32(*(const bf16x8*)(VB_ + 4096 + a4_1), pa1, O1);                    \
    O0 = MFMA32(*(const bf16x8*)(VB_ + a4_2),        pa2, O0);                    \
    O1 = MFMA32(*(const bf16x8*)(VB_ + 4096 + a4_2), pa2, O1);                    \
    O0 = MFMA32(*(const bf16x8*)(VB_ + a4_3),        pa3, O0);                    \
    O1 = MFMA32(*(const bf16x8*)(VB_ + 4096 + a4_3), pa3, O1);                    \
    __builtin_amdgcn_s_setprio(0);                                                \
    mcur = mnxt;                                                                  \
  } while (0)

__global__ __launch_bounds__(256, 4) void attn_kernel(
    const short* __restrict__ Qp, const short* __restrict__ Kp, const short* __restrict__ Vt,
    const unsigned long long* __restrict__ mbits, short* __restrict__ AO)
{
  // XCD-clustering remap (bijective): L = hi*128 + qt*8 + lo; pair = hi*8+lo
  int L  = blockIdx.x;
  int qt = (L >> 3) & 15;
  int p_ = ((L >> 7) << 3) | (L & 7);
  int h  = p_ & 15;
  int nb = p_ >> 4;
  int q0 = qt * 128;

  __shared__ __align__(16) char ldsK[2 * 8192];   // K tile [64k][64d], 2B, XOR-swizzled
  __shared__ __align__(16) char ldsV[2 * 8192];   // V^T tile [64d][64k], 2B, XOR-swizzled
  __shared__ __align__(16) float lutm[16][4];     // nibble -> additive mask {0,-16384}

  int tid = threadIdx.x, lane = tid & 63, w = tid >> 6;
  int l31 = lane & 31, hi5 = lane >> 5;
  int g8 = lane & 7, r8 = lane >> 3;
  int pp = lane & 7;
  unsigned sh4 = (unsigned)(hi5 * 4);

  if (tid < 64) {
    int e = tid >> 2, r = tid & 3;
    lutm[e][r] = ((e >> r) & 1) ? 0.f : -16384.f;
  }

  long long nh = (long long)(nb * HEADS + h);
  const char* Kb = (const char*)(Kp + nh * SEQ * HD);
  const char* Vb = (const char*)(Vt + nh * HD * SEQ);

  int kgo = (w * 8 + r8) * 128 + ((g8 ^ r8) << 4);
  int vgo = (w * 8 + r8) * 4096 + ((g8 ^ r8) << 4);
  int klo = w * 1024;

  int a4_0 = l31 * 128 + ((((0 | hi5) ^ pp)) << 4);
  int a4_1 = l31 * 128 + ((((2 | hi5) ^ pp)) << 4);
  int a4_2 = l31 * 128 + ((((4 | hi5) ^ pp)) << 4);
  int a4_3 = l31 * 128 + ((((6 | hi5) ^ pp)) << 4);

  int qrow = q0 + w * 32 + l31;
  const short* Qb = Qp + (nh * SEQ + qrow) * HD + hi5 * 8;
  bf16x8 qf0 = *(const bf16x8*)(Qb);
  bf16x8 qf1 = *(const bf16x8*)(Qb + 16);
  bf16x8 qf2 = *(const bf16x8*)(Qb + 32);
  bf16x8 qf3 = *(const bf16x8*)(Qb + 48);

  const unsigned long long* mptr = mbits + ((long long)nb * SEQ + qrow) * 32;

  f32x16 O0 = {}, O1 = {};
  float lsum = 0.f;

  glds16(Kb + kgo,          ldsK + klo);
  glds16(Kb + 4096 + kgo,   ldsK + 4096 + klo);
  glds16(Vb + vgo,          ldsV + klo);
  glds16(Vb + vgo + 131072, ldsV + 4096 + klo);
  unsigned long long mcur = mptr[0], mnxt = 0;

  for (int it = 0; it < 16; it++) {
    ATTN_ITER(0, it * 2);
    ATTN_ITER(1, it * 2 + 1);
  }

  lsum += __shfl_xor(lsum, 32);
  float inv = 1.f / lsum;

  short* aoRow = AO + ((long long)nb * SEQ + qrow) * EMBED + h * HD + hi5 * 4;
#pragma unroll
  for (int j = 0; j < 4; j++) {
    uint2 pk;
    pk.x = pkbf(O0[4 * j] * inv, O0[4 * j + 1] * inv);
    pk.y = pkbf(O0[4 * j + 2] * inv, O0[4 * j + 3] * inv);
    *(uint2*)(aoRow + j * 8) = pk;
    pk.x = pkbf(O1[4 * j] * inv, O1[4 * j + 1] * inv);
    pk.y = pkbf(O1[4 * j + 2] * inv, O1[4 * j + 3] * inv);
    *(uint2*)(aoRow + 32 + j * 8) = pk;
  }
}

// ---------------- output projection: 128x128 tile, BK=64, double-buffered (R5) ----------------
__global__ __launch_bounds__(512) void outproj_kernel(
    const short* __restrict__ AO, const short* __restrict__ Wob,
    const float* __restrict__ bo, float* __restrict__ out)
{
  int rt = blockIdx.x, ct = blockIdx.y;
  __shared__ __align__(16) short AtL[2][128 * 64];  // 2 x 16 KB
  __shared__ __align__(16) short BtL[2][128 * 64];  // 2 x 16 KB

  int tid = threadIdx.x, lane = tid & 63, w = tid >> 6, quad = lane >> 4, l15 = lane & 15;
  int r8b = tid >> 3, g8 = tid & 7;
  int swz = g8 ^ (r8b & 7);
  int s3 = l15 & 7;
  int o0 = (quad ^ s3) * 16;
  int o1 = ((quad + 4) ^ s3) * 16;

  int r0 = rt * 128, c0 = ct * 128;
  int wr = (w >> 1) * 32, wc = (w & 1) * 64;

  const char* Abase = (const char*)AO  + (long long)(r0 + r8b) * 2048 + swz * 16;
  const char* Bbase = (const char*)Wob + (long long)(c0 + r8b) * 2048 + swz * 16;
  unsigned lbase = (unsigned)tid * 16;

  f32x4 acc[2][4];
#pragma unroll
  for (int mi = 0; mi < 2; mi++)
#pragma unroll
    for (int ni = 0; ni < 4; ni++) acc[mi][ni] = (f32x4){0.f, 0.f, 0.f, 0.f};

  glds16(Abase,               (char*)AtL[0] + lbase);
  glds16(Abase + 64LL * 2048, (char*)AtL[0] + lbase + 8192);
  glds16(Bbase,               (char*)BtL[0] + lbase);
  glds16(Bbase + 64LL * 2048, (char*)BtL[0] + lbase + 8192);

  for (int kc = 0; kc < 16; kc++) {
    __syncthreads();
    const char* AB = (const char*)AtL[kc & 1];
    const char* BB = (const char*)BtL[kc & 1];
    if (kc < 15) {
      char* dA = (char*)AtL[(kc & 1) ^ 1] + lbase;
      char* dB = (char*)BtL[(kc & 1) ^ 1] + lbase;
      glds16(Abase + (kc + 1) * 128,               dA);
      glds16(Abase + 64LL * 2048 + (kc + 1) * 128, dA + 8192);
      glds16(Bbase + (kc + 1) * 128,               dB);
      glds16(Bbase + 64LL * 2048 + (kc + 1) * 128, dB + 8192);
    }

    bf16x8 af[2][2];
#pragma unroll
    for (int mi = 0; mi < 2; mi++) {
      int r = wr + mi * 16 + l15;
      af[mi][0] = *(const bf16x8*)(AB + r * 128 + o0);
      af[mi][1] = *(const bf16x8*)(AB + r * 128 + o1);
    }
    __builtin_amdgcn_s_setprio(1);
#pragma unroll
    for (int ni = 0; ni < 4; ni++) {
      int r = wc + ni * 16 + l15;
      bf16x8 b0 = *(const bf16x8*)(BB + r * 128 + o0);
      bf16x8 b1 = *(const bf16x8*)(BB + r * 128 + o1);
#pragma unroll
      for (int mi = 0; mi < 2; mi++) {
        acc[mi][ni] = __builtin_amdgcn_mfma_f32_16x16x32_bf16(af[mi][0], b0, acc[mi][ni], 0, 0, 0);
        acc[mi][ni] = __builtin_amdgcn_mfma_f32_16x16x32_bf16(af[mi][1], b1, acc[mi][ni], 0, 0, 0);
      }
    }
    __builtin_amdgcn_s_setprio(0);
  }

#pragma unroll
  for (int ni = 0; ni < 4; ni++) {
    float b = bo[c0 + wc + ni * 16 + l15];
#pragma unroll
    for (int mi = 0; mi < 2; mi++)
#pragma unroll
      for (int reg = 0; reg < 4; reg++) {
        int r = r0 + wr + mi * 16 + quad * 4 + reg;
        out[(long long)r * EMBED + c0 + wc + ni * 16 + l15] = acc[mi][ni][reg] + b;
      }
  }
}

extern "C" void kernel_launch(void* const* d_in, const int* in_sizes, int n_in,
                              void* d_out, int out_size, void* d_ws, size_t ws_size,
                              hipStream_t stream) {
  const float* values  = (const float*)d_in[0];
  const float* queries = (const float*)d_in[1];
  const float* keys    = (const float*)d_in[2];
  const int*   mask    = (const int*)d_in[3];
  const float* Wv = (const float*)d_in[4];
  const float* Wk = (const float*)d_in[5];
  const float* Wq = (const float*)d_in[6];
  const float* Wo = (const float*)d_in[7];
  const float* bo = (const float*)d_in[8];
  float* out = (float*)d_out;

  char* ws = (char*)d_ws;
  size_t off = 0;
  const size_t PROJ_BYTES = (size_t)NBATCH * HEADS * SEQ * HD * 2;  // 16 MiB
  short* Qp = (short*)(ws + off); off += PROJ_BYTES;
  short* Kp = (short*)(ws + off); off += PROJ_BYTES;
  short* Vt = (short*)(ws + off); off += PROJ_BYTES;
  short* AO = (short*)(ws + off); off += PROJ_BYTES;
  unsigned long long* mbits = (unsigned long long*)(ws + off);
  off += (size_t)NBATCH * SEQ * (SEQ / 64) * 8;  // 2 MiB
  short* Wob = (short*)(ws + off); off += (size_t)EMBED * EMBED * 2;  // 2 MiB
  short* WbQ = (short*)(ws + off); off += HD * HD * 2;
  short* WbK = (short*)(ws + off); off += HD * HD * 2;
  short* WbV = (short*)(ws + off); off += HD * HD * 2;

  cvt_all<<<dim3((EMBED * EMBED + 3 * HD * HD) / 4 / 256), dim3(256), 0, stream>>>(
      Wo, Wq, Wk, Wv, Wob, WbQ, WbK, WbV);

  mask_pack<<<dim3((NBATCH * SEQ * SEQ) / 1024), dim3(256), 0, stream>>>(mask, mbits);

  proj_kernel<<<dim3((NBATCH * SEQ) / 64, HEADS, 3), dim3(256), 0, stream>>>(
      queries, keys, values, WbQ, WbK, WbV, Qp, Kp, Vt);

  attn_kernel<<<dim3(SEQ / 128 * HEADS * NBATCH), dim3(256), 0, stream>>>(Qp, Kp, Vt, mbits, AO);

  outproj_kernel<<<dim3((NBATCH * SEQ) / 128, EMBED / 128), dim3(512), 0, stream>>>(AO, Wob, bo, out);
}